// Round 11
// baseline (46.323 us; speedup 1.0000x reference)
//
#include <hip/hip_runtime.h>

#define NEG_SLOPE 0.2f
#define EPS 1e-6f

// x: [B=4, C=64, V=3, N=32768] f32, W: [64,64] f32, out like x
// d[o,v,n] = sum_i W[o,i]*x[i,v,n]; out = dot>=0 ? x : x - 0.8*(dot/(dnsq+eps))*d
// bf16 MFMA (A=W frag, B=x frag), hi/lo 3-product split.
// Staging via global_load_lds (async DMA, no VGPR round-trip, no pack VALU).
// LDS = raw fp32, global-row-major [r=3i+v][64]; bank swizzle applied on the
// GLOBAL source address (rule 21 / m173): chunk ^= ((i>>3)&3)<<2.

#define C_CH 64
#define V_DIM 3
#define N_FULL 32768
#define NT 64
#define THREADS 512

typedef __attribute__((ext_vector_type(8))) short bf16x8;
typedef __attribute__((ext_vector_type(4))) float f32x4;

__device__ __forceinline__ ushort f2bf(float f) {
    union { float f; unsigned u; } v; v.f = f;
    unsigned r = v.u + 0x7FFFu + ((v.u >> 16) & 1u);  // RNE
    return (ushort)(r >> 16);
}
__device__ __forceinline__ float bf2f(ushort s) {
    union { unsigned u; float f; } v; v.u = ((unsigned)s) << 16; return v.f;
}
__device__ __forceinline__ unsigned f2u(float f) {
    union { float f; unsigned u; } v; v.f = f; return v.u;
}
__device__ __forceinline__ float u2f(unsigned u) {
    union { unsigned u; float f; } v; v.u = u; return v.f;
}

// ---- pre-kernel: split W fp32 -> Whi/Wlo bf16 (8 KB each), RNE both
__global__ void w_split_kernel(const float* __restrict__ W,
                               ushort* __restrict__ whi, ushort* __restrict__ wlo) {
    int i = blockIdx.x * 256 + threadIdx.x;
    if (i < C_CH * C_CH) {
        float w = W[i];
        ushort h = f2bf(w);
        whi[i] = h;
        wlo[i] = f2bf(w - bf2f(h));
    }
}

template<bool USE_WS>
__global__ __launch_bounds__(THREADS, 6)
void vn_dma64(const float* __restrict__ x,
              const float* __restrict__ Wf,
              const ushort* __restrict__ whi, const ushort* __restrict__ wlo,
              float* __restrict__ out) {
    // raw fp32, global-row order: row r = 3*i + v. 48 KB.
    __shared__ float xs[V_DIM * C_CH][NT];

    const int t    = threadIdx.x;
    const int tile = blockIdx.x;
    const int b    = tile >> 9;            // 512 tiles per batch
    const int n0   = (tile & 511) << 6;    // *64

    const float* xb = x + (size_t)b * (C_CH * V_DIM * N_FULL) + n0;

    const int lane = t & 63;
    const int w    = t >> 6;   // 0..7
    const int wo   = w >> 2;   // o-half -> 32 channels
    const int wn   = w & 3;    // n-quarter -> 16 cols
    const int l4   = lane & 15;
    const int hi   = lane >> 4;

    // ---- async DMA stage: 6 x 1KB per wave; source pre-swizzled for banks.
    // LDS linear dest: xs[r][(lane&15)*4..+3] <- global row r, chunk (lane&15)^s(i)
    #pragma unroll
    for (int it = 0; it < 6; ++it) {
        int r = 4 * (w * 6 + it) + (lane >> 4);   // global row 0..191
        int i = (r * 171) >> 9;                   // r/3 (exact for r<768)
        int chunk = (lane & 15) ^ (((i >> 3) & 3) << 2);
        const float* g = xb + (size_t)r * N_FULL + (chunk << 2);
        void* l = (char*)(&xs[0][0]) + (size_t)(w * 6 + it) * 1024 + (size_t)lane * 16;
        __builtin_amdgcn_global_load_lds(
            (const __attribute__((address_space(1))) unsigned*)g,
            (__attribute__((address_space(3))) unsigned*)l, 16, 0, 0);
    }

    // ---- A fragments (W) under the DMA shadow: row o = wo*32+m*16+l4,
    // k = kh*32+hi*8+j
    bf16x8 Ah[2][2], Al[2][2];
    if (USE_WS) {
        #pragma unroll
        for (int m = 0; m < 2; ++m)
            #pragma unroll
            for (int kh = 0; kh < 2; ++kh) {
                size_t off = (size_t)(wo * 32 + m * 16 + l4) * C_CH + kh * 32 + hi * 8;
                Ah[m][kh] = *(const bf16x8*)(whi + off);
                Al[m][kh] = *(const bf16x8*)(wlo + off);
            }
    } else {
        #pragma unroll
        for (int m = 0; m < 2; ++m)
            #pragma unroll
            for (int kh = 0; kh < 2; ++kh) {
                const float* wp = Wf + (size_t)(wo * 32 + m * 16 + l4) * C_CH + kh * 32 + hi * 8;
                float4 wa = *(const float4*)wp;
                float4 wb = *(const float4*)(wp + 4);
                float wf[8] = {wa.x, wa.y, wa.z, wa.w, wb.x, wb.y, wb.z, wb.w};
                bf16x8 h, l;
                #pragma unroll
                for (int j = 0; j < 8; ++j) {
                    ushort hb = f2bf(wf[j]);
                    h[j] = (short)hb;
                    l[j] = (short)f2bf(wf[j] - bf2f(hb));
                }
                Ah[m][kh] = h; Al[m][kh] = l;
            }
    }

    __syncthreads();   // drains vmcnt (DMA) + barrier

    f32x4 acc[2][3];
    #pragma unroll
    for (int m = 0; m < 2; ++m)
        #pragma unroll
        for (int v = 0; v < 3; ++v)
            acc[m][v] = (f32x4){0.f, 0.f, 0.f, 0.f};

    // ---- MFMA: B-frag rows rb = 3*(kh*32+hi*8+j)+v; swizzled col = g^(hi<<4)
    const int acol = (wn * 16 + l4) ^ (hi << 4);  // const per thread
    #pragma unroll
    for (int v = 0; v < 3; ++v) {
        #pragma unroll
        for (int kh = 0; kh < 2; ++kh) {
            const int ib = kh * 32 + hi * 8;
            float f[8];
            #pragma unroll
            for (int j = 0; j < 8; ++j)
                f[j] = xs[3 * (ib + j) + v][acol];
            // hi = truncated bf16 (pure perm), lo = trunc(f - hi) (exact residual)
            union { bf16x8 v8; unsigned d[4]; } BH, BL;
            unsigned rl[8];
            #pragma unroll
            for (int j = 0; j < 8; ++j)
                rl[j] = f2u(f[j] - u2f(f2u(f[j]) & 0xffff0000u));
            #pragma unroll
            for (int q = 0; q < 4; ++q) {
                BH.d[q] = __builtin_amdgcn_perm(f2u(f[2 * q + 1]), f2u(f[2 * q]), 0x07060302u);
                BL.d[q] = __builtin_amdgcn_perm(rl[2 * q + 1], rl[2 * q], 0x07060302u);
            }
            #pragma unroll
            for (int m = 0; m < 2; ++m) {
                acc[m][v] = __builtin_amdgcn_mfma_f32_16x16x32_bf16(Ah[m][kh], BH.v8, acc[m][v], 0, 0, 0);
                acc[m][v] = __builtin_amdgcn_mfma_f32_16x16x32_bf16(Ah[m][kh], BL.v8, acc[m][v], 0, 0, 0);
                acc[m][v] = __builtin_amdgcn_mfma_f32_16x16x32_bf16(Al[m][kh], BH.v8, acc[m][v], 0, 0, 0);
            }
        }
    }

    // ---- epilogue: C/D col=l4 (n), row=hi*4+r (o within 16); exact fp32 x
    const int n = wn * 16 + l4;
    float* ob = out + (size_t)b * (C_CH * V_DIM * N_FULL) + n0 + n;
    #pragma unroll
    for (int m = 0; m < 2; ++m) {
        #pragma unroll
        for (int rr = 0; rr < 4; ++rr) {
            const int o = wo * 32 + m * 16 + hi * 4 + rr;
            const int ecol = n ^ (((m * 2 + (hi >> 1)) & 3) << 4);
            float xv[3], dv[3];
            #pragma unroll
            for (int v = 0; v < 3; ++v) {
                xv[v] = xs[3 * o + v][ecol];
                dv[v] = acc[m][v][rr];
            }
            float dot  = xv[0] * dv[0] + xv[1] * dv[1] + xv[2] * dv[2];
            float dnsq = dv[0] * dv[0] + dv[1] * dv[1] + dv[2] * dv[2];
            float f = (1.0f - NEG_SLOPE) * dot * __builtin_amdgcn_rcpf(dnsq + EPS);
            f = (dot >= 0.f) ? 0.f : f;
            float o0 = fmaf(-f, dv[0], xv[0]);
            float o1 = fmaf(-f, dv[1], xv[1]);
            float o2 = fmaf(-f, dv[2], xv[2]);
            float* op = ob + (size_t)o * (V_DIM * N_FULL);
            op[0 * N_FULL] = o0;
            op[1 * N_FULL] = o1;
            op[2 * N_FULL] = o2;
        }
    }
}

extern "C" void kernel_launch(void* const* d_in, const int* in_sizes, int n_in,
                              void* d_out, int out_size, void* d_ws, size_t ws_size,
                              hipStream_t stream) {
    const float* x = (const float*)d_in[0];
    const float* W = (const float*)d_in[1];
    float* out = (float*)d_out;

    const int B = 4;
    const int blocks = B * (N_FULL / NT);  // 2048

    if (ws_size >= 2u * C_CH * C_CH * sizeof(ushort)) {
        ushort* whi = (ushort*)d_ws;
        ushort* wlo = whi + C_CH * C_CH;
        w_split_kernel<<<(C_CH * C_CH + 255) / 256, 256, 0, stream>>>(W, whi, wlo);
        vn_dma64<true><<<blocks, THREADS, 0, stream>>>(x, W, whi, wlo, out);
    } else {
        vn_dma64<false><<<blocks, THREADS, 0, stream>>>(x, W, nullptr, nullptr, out);
    }
}